// Round 1
// baseline (318.242 us; speedup 1.0000x reference)
//
#include <hip/hip_runtime.h>
#include <hip/hip_bf16.h>

typedef __bf16 bf16_t;
typedef __attribute__((ext_vector_type(8))) __bf16 bf16x8;
typedef __attribute__((ext_vector_type(4))) float f32x4;

// dims: B=8 S=1024 D=1024 H=16 hd=64
#define QSCALE 0.18033688011112042f   // (1/sqrt(64)) * log2(e)

// ws layout (bytes). Ob aliases Xb (Xb dead after gemm_qkv).
#define OFF_XB      ((size_t)0)                       // bf16 [8192][1024]  16.78MB
#define OFF_WQKVT   ((size_t)16777216)                // bf16 [3072][1024]   6.29MB
#define OFF_WPROJT  ((size_t)(16777216 + 6291456))    // bf16 [1024][1024]   2.10MB
#define OFF_Q       ((size_t)(16777216 + 6291456 + 2097152)) // bf16 [128][1024][64]
#define OFF_K       (OFF_Q + (size_t)16777216)
#define OFF_V       (OFF_K + (size_t)16777216)        // transposed: [128][64][1024]
#define OFF_O       OFF_XB                            // bf16 [8192][1024] (alias)

typedef const __attribute__((address_space(1))) void* as1cv;
typedef __attribute__((address_space(3))) void* as3v;

__device__ __forceinline__ void load_lds16(const void* g, void* l) {
  __builtin_amdgcn_global_load_lds((as1cv)g, (as3v)l, 16, 0, 0);
}

__device__ __forceinline__ f32x4 mfma16(bf16x8 a, bf16x8 b, f32x4 c) {
  return __builtin_amdgcn_mfma_f32_16x16x32_bf16(a, b, c, 0, 0, 0);
}

__device__ __forceinline__ float rmax16(float v) {
  v = fmaxf(v, __shfl_xor(v, 1, 16));
  v = fmaxf(v, __shfl_xor(v, 2, 16));
  v = fmaxf(v, __shfl_xor(v, 4, 16));
  v = fmaxf(v, __shfl_xor(v, 8, 16));
  return v;
}
__device__ __forceinline__ float rsum16(float v) {
  v += __shfl_xor(v, 1, 16);
  v += __shfl_xor(v, 2, 16);
  v += __shfl_xor(v, 4, 16);
  v += __shfl_xor(v, 8, 16);
  return v;
}

// ---------------- conversion kernels ----------------

__global__ __launch_bounds__(256) void cvt_bf16_kernel(
    const float* __restrict__ in, bf16_t* __restrict__ out, int n8) {
  int i = blockIdx.x * blockDim.x + threadIdx.x;
  if (i >= n8) return;
  const float4* p = (const float4*)in + (size_t)i * 2;
  float4 a = p[0], b = p[1];
  bf16x8 o;
  o[0] = (bf16_t)a.x; o[1] = (bf16_t)a.y; o[2] = (bf16_t)a.z; o[3] = (bf16_t)a.w;
  o[4] = (bf16_t)b.x; o[5] = (bf16_t)b.y; o[6] = (bf16_t)b.z; o[7] = (bf16_t)b.w;
  ((bf16x8*)out)[i] = o;
}

// Wt[n][k] = W[k][n], fp32 -> bf16
__global__ __launch_bounds__(256) void transpose_cvt(
    const float* __restrict__ W, bf16_t* __restrict__ Wt, int rows, int cols) {
  __shared__ float t[32][33];
  const int c0 = blockIdx.x * 32, r0 = blockIdx.y * 32;
  const int tx = threadIdx.x, ty = threadIdx.y;
  for (int rr = ty; rr < 32; rr += 8)
    t[rr][tx] = W[(size_t)(r0 + rr) * cols + c0 + tx];
  __syncthreads();
  for (int rr = ty; rr < 32; rr += 8)
    Wt[(size_t)(c0 + rr) * rows + r0 + tx] = (bf16_t)t[tx][rr];
}

// ---------------- GEMM mainloop (128x128 tile, BK=64, K=1024, lda=ldb=1024) ----------------

__device__ __forceinline__ void gemm_mainloop_1024(
    const bf16_t* __restrict__ A, const bf16_t* __restrict__ Bt,
    int m0, int n0, bf16_t* Alds, bf16_t* Blds, f32x4 acc[4][4]) {
  const int tid = threadIdx.x;
  const int w = tid >> 6, lane = tid & 63;
  const int wr = w >> 1, wc = w & 1;
  const int lr = lane & 15, lg = lane >> 4;
#pragma unroll
  for (int m = 0; m < 4; ++m)
#pragma unroll
    for (int n = 0; n < 4; ++n)
      acc[m][n] = f32x4{0.f, 0.f, 0.f, 0.f};

  const int crow = lane >> 3;        // 0..7 row within 8-row chunk
  const int cels = (lane & 7) * 8;   // element offset within row

  for (int kt = 0; kt < 16; ++kt) {
    const int k0 = kt * 64;
#pragma unroll
    for (int it = 0; it < 4; ++it) {
      const int c = it * 4 + w;                // chunk 0..15, uniform per wave
      const int rA = c * 8 + crow;             // tile row 0..127
      load_lds16(A + (size_t)(m0 + rA) * 1024 + k0 + cels, (char*)Alds + c * 1024);
      load_lds16(Bt + (size_t)(n0 + rA) * 1024 + k0 + cels, (char*)Blds + c * 1024);
    }
    asm volatile("s_waitcnt vmcnt(0)" ::: "memory");
    __syncthreads();

    bf16x8 af[4][2], bfr[4][2];
#pragma unroll
    for (int m = 0; m < 4; ++m)
#pragma unroll
      for (int kk = 0; kk < 2; ++kk)
        af[m][kk] = *(const bf16x8*)(Alds + (wr * 64 + m * 16 + lr) * 64 + kk * 32 + lg * 8);
#pragma unroll
    for (int n = 0; n < 4; ++n)
#pragma unroll
      for (int kk = 0; kk < 2; ++kk)
        bfr[n][kk] = *(const bf16x8*)(Blds + (wc * 64 + n * 16 + lr) * 64 + kk * 32 + lg * 8);
#pragma unroll
    for (int kk = 0; kk < 2; ++kk)
#pragma unroll
      for (int m = 0; m < 4; ++m)
#pragma unroll
        for (int n = 0; n < 4; ++n)
          acc[m][n] = mfma16(af[m][kk], bfr[n][kk], acc[m][n]);
    __syncthreads();
  }
}

// ---------------- GEMM1: X @ Wqkv^T -> scatter Q(scaled)/K/V(transposed) bf16 ----------------

__global__ __launch_bounds__(256) void gemm_qkv(
    const bf16_t* __restrict__ A, const bf16_t* __restrict__ Bt,
    const float* __restrict__ bias,
    bf16_t* __restrict__ Qh, bf16_t* __restrict__ Kh, bf16_t* __restrict__ Vt) {
  __shared__ alignas(128) bf16_t Alds[128 * 64];
  __shared__ alignas(128) bf16_t Blds[128 * 64];
  const int m0 = blockIdx.x * 128, n0 = blockIdx.y * 128;
  f32x4 acc[4][4];
  gemm_mainloop_1024(A, Bt, m0, n0, Alds, Blds, acc);

  const int tid = threadIdx.x, w = tid >> 6, lane = tid & 63;
  const int wr = w >> 1, wc = w & 1, lr = lane & 15, lg = lane >> 4;
  const int section = n0 >> 10;  // 0=Q 1=K 2=V (uniform per block)
#pragma unroll
  for (int n = 0; n < 4; ++n) {
    const int c = n0 + wc * 64 + n * 16 + lr;   // global col in [0,3072)
    const float bi = bias[c];
    const int d1024 = c & 1023;
    const int h = d1024 >> 6, d = d1024 & 63;
#pragma unroll
    for (int m = 0; m < 4; ++m) {
#pragma unroll
      for (int j = 0; j < 4; ++j) {
        const int r = m0 + wr * 64 + m * 16 + lg * 4 + j;  // token index
        const int b = r >> 10, s = r & 1023;
        const size_t hb = ((size_t)(b * 16 + h)) << 16;
        const float v = acc[m][n][j] + bi;
        if (section == 0)      Qh[hb + (size_t)s * 64 + d] = (bf16_t)(v * QSCALE);
        else if (section == 1) Kh[hb + (size_t)s * 64 + d] = (bf16_t)v;
        else                   Vt[hb + (size_t)d * 1024 + s] = (bf16_t)v;
      }
    }
  }
}

// ---------------- GEMM2: O @ Wproj^T + b -> fp32 out ----------------

__global__ __launch_bounds__(256) void gemm_out(
    const bf16_t* __restrict__ A, const bf16_t* __restrict__ Bt,
    const float* __restrict__ bias, float* __restrict__ out) {
  __shared__ alignas(128) bf16_t Alds[128 * 64];
  __shared__ alignas(128) bf16_t Blds[128 * 64];
  const int m0 = blockIdx.x * 128, n0 = blockIdx.y * 128;
  f32x4 acc[4][4];
  gemm_mainloop_1024(A, Bt, m0, n0, Alds, Blds, acc);

  const int tid = threadIdx.x, w = tid >> 6, lane = tid & 63;
  const int wr = w >> 1, wc = w & 1, lr = lane & 15, lg = lane >> 4;
#pragma unroll
  for (int n = 0; n < 4; ++n) {
    const int c = n0 + wc * 64 + n * 16 + lr;
    const float bi = bias[c];
#pragma unroll
    for (int m = 0; m < 4; ++m)
#pragma unroll
      for (int j = 0; j < 4; ++j) {
        const int r = m0 + wr * 64 + m * 16 + lg * 4 + j;
        out[(size_t)r * 1024 + c] = acc[m][n][j] + bi;
      }
  }
}

// ---------------- flash attention: 4 waves x 32 q-rows, KV tiles of 64 ----------------

__global__ __launch_bounds__(256) void attn_kernel(
    const bf16_t* __restrict__ Qh, const bf16_t* __restrict__ Kh,
    const bf16_t* __restrict__ Vt, bf16_t* __restrict__ Ob) {
  __shared__ alignas(128) bf16_t Klds[64 * 64];     // [kv][d], XOR-swizzled
  __shared__ alignas(128) bf16_t Vlds[64 * 64];     // [d][kv], XOR-swizzled
  __shared__ alignas(128) bf16_t Plds[4][32 * 64];  // per-wave P, XOR-swizzled

  const int blk = blockIdx.x;           // 1024 = 128 heads * 8 q-tiles
  const int bh = blk >> 3, qt = blk & 7;
  const int b = bh >> 4, h = bh & 15;
  const int tid = threadIdx.x, w = tid >> 6, lane = tid & 63;
  const int lr = lane & 15, lg = lane >> 4;
  const size_t base = (size_t)bh << 16;   // *65536 elements per head
  bf16_t* Pw = &Plds[w][0];

  // Q fragments held in registers for the whole KV loop (pre-scaled in gemm_qkv)
  const int qrow0 = qt * 128 + w * 32;
  bf16x8 qf[2][2];
#pragma unroll
  for (int m = 0; m < 2; ++m)
#pragma unroll
    for (int kk = 0; kk < 2; ++kk)
      qf[m][kk] = *(const bf16x8*)(Qh + base + (size_t)(qrow0 + m * 16 + lr) * 64 + kk * 32 + lg * 8);

  f32x4 oacc[2][4];
  float mreg[2][4], lreg[2][4];
#pragma unroll
  for (int m = 0; m < 2; ++m) {
#pragma unroll
    for (int n = 0; n < 4; ++n) oacc[m][n] = f32x4{0.f, 0.f, 0.f, 0.f};
#pragma unroll
    for (int j = 0; j < 4; ++j) { mreg[m][j] = -1e30f; lreg[m][j] = 0.f; }
  }

  // staging geometry: chunk = 8 rows x 128B; source slot pre-swizzled so that
  // linear LDS + XOR-read is the identity (rule #21 both-sides pattern)
  const int srow = lane >> 3;                               // 0..7
  const int sslot = (((lane & 7) ^ srow) << 3);             // swizzled element offset

  for (int kt = 0; kt < 16; ++kt) {
#pragma unroll
    for (int it = 0; it < 2; ++it) {
      const int c = it * 4 + w;          // chunk 0..7, uniform per wave
      const int r = c * 8 + srow;        // tile row 0..63
      load_lds16(Kh + base + (size_t)(kt * 64 + r) * 64 + sslot, (char*)Klds + c * 1024);
      load_lds16(Vt + base + (size_t)r * 1024 + kt * 64 + sslot, (char*)Vlds + c * 1024);
    }
    asm volatile("s_waitcnt vmcnt(0)" ::: "memory");
    __syncthreads();

    // S' = Q K^T (already includes scale*log2e)
    f32x4 sacc[2][4];
#pragma unroll
    for (int m = 0; m < 2; ++m)
#pragma unroll
      for (int n = 0; n < 4; ++n) sacc[m][n] = f32x4{0.f, 0.f, 0.f, 0.f};
#pragma unroll
    for (int kk = 0; kk < 2; ++kk) {
      bf16x8 kf[4];
#pragma unroll
      for (int n = 0; n < 4; ++n) {
        const int row = n * 16 + lr;
        kf[n] = *(const bf16x8*)((const char*)Klds + row * 128 +
                                 ((kk * 64 + lg * 16) ^ ((row & 7) << 4)));
      }
#pragma unroll
      for (int m = 0; m < 2; ++m)
#pragma unroll
        for (int n = 0; n < 4; ++n)
          sacc[m][n] = mfma16(qf[m][kk], kf[n], sacc[m][n]);
    }

    // online softmax (base-2) + P -> swizzled LDS (bf16)
#pragma unroll
    for (int m = 0; m < 2; ++m) {
#pragma unroll
      for (int j = 0; j < 4; ++j) {
        const float s0 = sacc[m][0][j], s1 = sacc[m][1][j];
        const float s2 = sacc[m][2][j], s3 = sacc[m][3][j];
        float tm = fmaxf(fmaxf(s0, s1), fmaxf(s2, s3));
        tm = rmax16(tm);
        const float mold = mreg[m][j];
        const float mnew = fmaxf(mold, tm);
        const float corr = exp2f(mold - mnew);
        const float p0 = exp2f(s0 - mnew), p1 = exp2f(s1 - mnew);
        const float p2 = exp2f(s2 - mnew), p3 = exp2f(s3 - mnew);
        const float ps = rsum16(p0 + p1 + p2 + p3);
        mreg[m][j] = mnew;
        lreg[m][j] = lreg[m][j] * corr + ps;
#pragma unroll
        for (int n = 0; n < 4; ++n) oacc[m][n][j] *= corr;
        const int prow = m * 16 + lg * 4 + j;
        const int rx = (prow & 7) << 4;
        char* pb = (char*)Pw + prow * 128;
        *(bf16_t*)(pb + (((0 * 16 + lr) * 2) ^ rx)) = (bf16_t)p0;
        *(bf16_t*)(pb + (((1 * 16 + lr) * 2) ^ rx)) = (bf16_t)p1;
        *(bf16_t*)(pb + (((2 * 16 + lr) * 2) ^ rx)) = (bf16_t)p2;
        *(bf16_t*)(pb + (((3 * 16 + lr) * 2) ^ rx)) = (bf16_t)p3;
      }
    }
    asm volatile("s_waitcnt lgkmcnt(0)" ::: "memory");

    // O += P V  (A = P from Plds, B = V from Vlds[d][kv], both contiguous reads)
#pragma unroll
    for (int kk = 0; kk < 2; ++kk) {
      bf16x8 pf[2], vf[4];
#pragma unroll
      for (int m = 0; m < 2; ++m) {
        const int row = m * 16 + lr;
        pf[m] = *(const bf16x8*)((const char*)Pw + row * 128 +
                                 ((kk * 64 + lg * 16) ^ ((row & 7) << 4)));
      }
#pragma unroll
      for (int n = 0; n < 4; ++n) {
        const int row = n * 16 + lr;
        vf[n] = *(const bf16x8*)((const char*)Vlds + row * 128 +
                                 ((kk * 64 + lg * 16) ^ ((row & 7) << 4)));
      }
#pragma unroll
      for (int m = 0; m < 2; ++m)
#pragma unroll
        for (int n = 0; n < 4; ++n)
          oacc[m][n] = mfma16(pf[m], vf[n], oacc[m][n]);
    }
    __syncthreads();
  }

  // epilogue: O /= l, write [b][s][h*64+d] bf16
#pragma unroll
  for (int m = 0; m < 2; ++m)
#pragma unroll
    for (int j = 0; j < 4; ++j) {
      const float inv = 1.0f / lreg[m][j];
      const int s = qrow0 + m * 16 + lg * 4 + j;
#pragma unroll
      for (int n = 0; n < 4; ++n)
        Ob[(size_t)(b * 1024 + s) * 1024 + h * 64 + n * 16 + lr] =
            (bf16_t)(oacc[m][n][j] * inv);
    }
}

// ---------------- launch ----------------

extern "C" void kernel_launch(void* const* d_in, const int* in_sizes, int n_in,
                              void* d_out, int out_size, void* d_ws, size_t ws_size,
                              hipStream_t stream) {
  const float* x     = (const float*)d_in[0];
  const float* Wqkv  = (const float*)d_in[1];
  const float* bqkv  = (const float*)d_in[2];
  const float* Wproj = (const float*)d_in[3];
  const float* bproj = (const float*)d_in[4];
  float* out = (float*)d_out;
  char* ws = (char*)d_ws;

  bf16_t* Xb  = (bf16_t*)(ws + OFF_XB);
  bf16_t* Wqt = (bf16_t*)(ws + OFF_WQKVT);
  bf16_t* Wpt = (bf16_t*)(ws + OFF_WPROJT);
  bf16_t* Qh  = (bf16_t*)(ws + OFF_Q);
  bf16_t* Kh  = (bf16_t*)(ws + OFF_K);
  bf16_t* Vt  = (bf16_t*)(ws + OFF_V);
  bf16_t* Ob  = (bf16_t*)(ws + OFF_O);  // aliases Xb (dead after gemm_qkv)

  cvt_bf16_kernel<<<4096, 256, 0, stream>>>(x, Xb, 1048576);
  transpose_cvt<<<dim3(96, 32), dim3(32, 8), 0, stream>>>(Wqkv, Wqt, 1024, 3072);
  transpose_cvt<<<dim3(32, 32), dim3(32, 8), 0, stream>>>(Wproj, Wpt, 1024, 1024);
  gemm_qkv<<<dim3(64, 24), 256, 0, stream>>>(Xb, Wqt, bqkv, Qh, Kh, Vt);
  attn_kernel<<<1024, 256, 0, stream>>>(Qh, Kh, Vt, Ob);
  gemm_out<<<dim3(64, 8), 256, 0, stream>>>(Ob, Wpt, bproj, out);
}

// Round 2
// 267.378 us; speedup vs baseline: 1.1902x; 1.1902x over previous
//
#include <hip/hip_runtime.h>
#include <hip/hip_bf16.h>

typedef __bf16 bf16_t;
typedef __attribute__((ext_vector_type(8))) __bf16 bf16x8;
typedef __attribute__((ext_vector_type(4))) float f32x4;

// dims: B=8 S=1024 D=1024 H=16 hd=64
#define QSCALE 0.18033688011112042f   // (1/sqrt(64)) * log2(e)
#define RESCALE_THR 11.5f             // defer-max threshold in log2 units (~8 nats)

// ws layout (bytes). Ob aliases Xb (Xb dead after gemm_qkv).
#define OFF_XB      ((size_t)0)                       // bf16 [8192][1024]  16.78MB
#define OFF_WQKVT   ((size_t)16777216)                // bf16 [3072][1024]   6.29MB
#define OFF_WPROJT  ((size_t)(16777216 + 6291456))    // bf16 [1024][1024]   2.10MB
#define OFF_Q       ((size_t)(16777216 + 6291456 + 2097152)) // bf16 [128][1024][64]
#define OFF_K       (OFF_Q + (size_t)16777216)
#define OFF_V       (OFF_K + (size_t)16777216)        // transposed: [128][64][1024]
#define OFF_O       OFF_XB                            // bf16 [8192][1024] (alias)

typedef const __attribute__((address_space(1))) void* as1cv;
typedef __attribute__((address_space(3))) void* as3v;

__device__ __forceinline__ void load_lds16(const void* g, void* l) {
  __builtin_amdgcn_global_load_lds((as1cv)g, (as3v)l, 16, 0, 0);
}

__device__ __forceinline__ f32x4 mfma16(bf16x8 a, bf16x8 b, f32x4 c) {
  return __builtin_amdgcn_mfma_f32_16x16x32_bf16(a, b, c, 0, 0, 0);
}

__device__ __forceinline__ float rmax16(float v) {
  v = fmaxf(v, __shfl_xor(v, 1, 16));
  v = fmaxf(v, __shfl_xor(v, 2, 16));
  v = fmaxf(v, __shfl_xor(v, 4, 16));
  v = fmaxf(v, __shfl_xor(v, 8, 16));
  return v;
}
__device__ __forceinline__ float rsum16(float v) {
  v += __shfl_xor(v, 1, 16);
  v += __shfl_xor(v, 2, 16);
  v += __shfl_xor(v, 4, 16);
  v += __shfl_xor(v, 8, 16);
  return v;
}

// ---------------- conversion kernels ----------------

__global__ __launch_bounds__(256) void cvt_bf16_kernel(
    const float* __restrict__ in, bf16_t* __restrict__ out, int n8) {
  int i = blockIdx.x * blockDim.x + threadIdx.x;
  if (i >= n8) return;
  const float4* p = (const float4*)in + (size_t)i * 2;
  float4 a = p[0], b = p[1];
  bf16x8 o;
  o[0] = (bf16_t)a.x; o[1] = (bf16_t)a.y; o[2] = (bf16_t)a.z; o[3] = (bf16_t)a.w;
  o[4] = (bf16_t)b.x; o[5] = (bf16_t)b.y; o[6] = (bf16_t)b.z; o[7] = (bf16_t)b.w;
  ((bf16x8*)out)[i] = o;
}

// Wt[n][k] = W[k][n], fp32 -> bf16
__global__ __launch_bounds__(256) void transpose_cvt(
    const float* __restrict__ W, bf16_t* __restrict__ Wt, int rows, int cols) {
  __shared__ float t[32][33];
  const int c0 = blockIdx.x * 32, r0 = blockIdx.y * 32;
  const int tx = threadIdx.x, ty = threadIdx.y;
  for (int rr = ty; rr < 32; rr += 8)
    t[rr][tx] = W[(size_t)(r0 + rr) * cols + c0 + tx];
  __syncthreads();
  for (int rr = ty; rr < 32; rr += 8)
    Wt[(size_t)(c0 + rr) * rows + r0 + tx] = (bf16_t)t[tx][rr];
}

// ---------------- GEMM mainloop (128x128 tile, BK=64, K=1024, lda=ldb=1024) ----------------

__device__ __forceinline__ void gemm_mainloop_1024(
    const bf16_t* __restrict__ A, const bf16_t* __restrict__ Bt,
    int m0, int n0, bf16_t* Alds, bf16_t* Blds, f32x4 acc[4][4]) {
  const int tid = threadIdx.x;
  const int w = tid >> 6, lane = tid & 63;
  const int wr = w >> 1, wc = w & 1;
  const int lr = lane & 15, lg = lane >> 4;
#pragma unroll
  for (int m = 0; m < 4; ++m)
#pragma unroll
    for (int n = 0; n < 4; ++n)
      acc[m][n] = f32x4{0.f, 0.f, 0.f, 0.f};

  const int crow = lane >> 3;        // 0..7 row within 8-row chunk
  const int cels = (lane & 7) * 8;   // element offset within row

  for (int kt = 0; kt < 16; ++kt) {
    const int k0 = kt * 64;
#pragma unroll
    for (int it = 0; it < 4; ++it) {
      const int c = it * 4 + w;                // chunk 0..15, uniform per wave
      const int rA = c * 8 + crow;             // tile row 0..127
      load_lds16(A + (size_t)(m0 + rA) * 1024 + k0 + cels, (char*)Alds + c * 1024);
      load_lds16(Bt + (size_t)(n0 + rA) * 1024 + k0 + cels, (char*)Blds + c * 1024);
    }
    asm volatile("s_waitcnt vmcnt(0)" ::: "memory");
    __syncthreads();

    bf16x8 af[4][2], bfr[4][2];
#pragma unroll
    for (int m = 0; m < 4; ++m)
#pragma unroll
      for (int kk = 0; kk < 2; ++kk)
        af[m][kk] = *(const bf16x8*)(Alds + (wr * 64 + m * 16 + lr) * 64 + kk * 32 + lg * 8);
#pragma unroll
    for (int n = 0; n < 4; ++n)
#pragma unroll
      for (int kk = 0; kk < 2; ++kk)
        bfr[n][kk] = *(const bf16x8*)(Blds + (wc * 64 + n * 16 + lr) * 64 + kk * 32 + lg * 8);
#pragma unroll
    for (int kk = 0; kk < 2; ++kk)
#pragma unroll
      for (int m = 0; m < 4; ++m)
#pragma unroll
        for (int n = 0; n < 4; ++n)
          acc[m][n] = mfma16(af[m][kk], bfr[n][kk], acc[m][n]);
    __syncthreads();
  }
}

// ---------------- GEMM1: X @ Wqkv^T -> scatter Q(scaled)/K/V(transposed) bf16 ----------------

__global__ __launch_bounds__(256) void gemm_qkv(
    const bf16_t* __restrict__ A, const bf16_t* __restrict__ Bt,
    const float* __restrict__ bias,
    bf16_t* __restrict__ Qh, bf16_t* __restrict__ Kh, bf16_t* __restrict__ Vt) {
  __shared__ alignas(128) bf16_t Alds[128 * 64];
  __shared__ alignas(128) bf16_t Blds[128 * 64];
  const int m0 = blockIdx.x * 128, n0 = blockIdx.y * 128;
  f32x4 acc[4][4];
  gemm_mainloop_1024(A, Bt, m0, n0, Alds, Blds, acc);

  const int tid = threadIdx.x, w = tid >> 6, lane = tid & 63;
  const int wr = w >> 1, wc = w & 1, lr = lane & 15, lg = lane >> 4;
  const int section = n0 >> 10;  // 0=Q 1=K 2=V (uniform per block)
#pragma unroll
  for (int n = 0; n < 4; ++n) {
    const int c = n0 + wc * 64 + n * 16 + lr;   // global col in [0,3072)
    const float bi = bias[c];
    const int d1024 = c & 1023;
    const int h = d1024 >> 6, d = d1024 & 63;
#pragma unroll
    for (int m = 0; m < 4; ++m) {
#pragma unroll
      for (int j = 0; j < 4; ++j) {
        const int r = m0 + wr * 64 + m * 16 + lg * 4 + j;  // token index
        const int b = r >> 10, s = r & 1023;
        const size_t hb = ((size_t)(b * 16 + h)) << 16;
        const float v = acc[m][n][j] + bi;
        if (section == 0)      Qh[hb + (size_t)s * 64 + d] = (bf16_t)(v * QSCALE);
        else if (section == 1) Kh[hb + (size_t)s * 64 + d] = (bf16_t)v;
        else                   Vt[hb + (size_t)d * 1024 + s] = (bf16_t)v;
      }
    }
  }
}

// ---------------- GEMM2: O @ Wproj^T + b -> fp32 out ----------------

__global__ __launch_bounds__(256) void gemm_out(
    const bf16_t* __restrict__ A, const bf16_t* __restrict__ Bt,
    const float* __restrict__ bias, float* __restrict__ out) {
  __shared__ alignas(128) bf16_t Alds[128 * 64];
  __shared__ alignas(128) bf16_t Blds[128 * 64];
  const int m0 = blockIdx.x * 128, n0 = blockIdx.y * 128;
  f32x4 acc[4][4];
  gemm_mainloop_1024(A, Bt, m0, n0, Alds, Blds, acc);

  const int tid = threadIdx.x, w = tid >> 6, lane = tid & 63;
  const int wr = w >> 1, wc = w & 1, lr = lane & 15, lg = lane >> 4;
#pragma unroll
  for (int n = 0; n < 4; ++n) {
    const int c = n0 + wc * 64 + n * 16 + lr;
    const float bi = bias[c];
#pragma unroll
    for (int m = 0; m < 4; ++m)
#pragma unroll
      for (int j = 0; j < 4; ++j) {
        const int r = m0 + wr * 64 + m * 16 + lg * 4 + j;
        out[(size_t)r * 1024 + c] = acc[m][n][j] + bi;
      }
  }
}

// ---------------- flash attention: 4 waves x 32 q-rows, KV tiles of 64 ----------------
// dbuf K/V prefetch (T3-minimum 2-phase), setprio around MFMA (T5),
// defer-max rescale (T13), launch_bounds(256,4) to force VGPR<=128.

__global__ __launch_bounds__(256, 4) void attn_kernel(
    const bf16_t* __restrict__ Qh, const bf16_t* __restrict__ Kh,
    const bf16_t* __restrict__ Vt, bf16_t* __restrict__ Ob) {
  __shared__ alignas(128) bf16_t Klds[2][64 * 64];  // [kv][d], XOR-swizzled
  __shared__ alignas(128) bf16_t Vlds[2][64 * 64];  // [d][kv], XOR-swizzled
  __shared__ alignas(128) bf16_t Plds[4][32 * 64];  // per-wave P, XOR-swizzled

  const int blk = blockIdx.x;           // 1024 = 128 heads * 8 q-tiles
  const int bh = blk >> 3, qt = blk & 7;
  const int b = bh >> 4, h = bh & 15;
  const int tid = threadIdx.x, w = tid >> 6, lane = tid & 63;
  const int lr = lane & 15, lg = lane >> 4;
  const size_t base = (size_t)bh << 16;   // *65536 elements per head
  bf16_t* Pw = &Plds[w][0];

  // Q fragments held in registers for the whole KV loop (pre-scaled in gemm_qkv)
  const int qrow0 = qt * 128 + w * 32;
  bf16x8 qf[2][2];
#pragma unroll
  for (int m = 0; m < 2; ++m)
#pragma unroll
    for (int kk = 0; kk < 2; ++kk)
      qf[m][kk] = *(const bf16x8*)(Qh + base + (size_t)(qrow0 + m * 16 + lr) * 64 + kk * 32 + lg * 8);

  f32x4 oacc[2][4];
  float mreg[2][4], lreg[2][4];
#pragma unroll
  for (int m = 0; m < 2; ++m) {
#pragma unroll
    for (int n = 0; n < 4; ++n) oacc[m][n] = f32x4{0.f, 0.f, 0.f, 0.f};
#pragma unroll
    for (int j = 0; j < 4; ++j) { mreg[m][j] = -1e30f; lreg[m][j] = 0.f; }
  }

  // staging geometry: chunk = 8 rows x 128B; source slot pre-swizzled so that
  // linear LDS + XOR-read is the identity (rule #21 both-sides pattern)
  const int srow = lane >> 3;                               // 0..7
  const int sslot = (((lane & 7) ^ srow) << 3);             // swizzled element offset

  // stage tile kt into buffer bsel
#define STAGE_KV(bsel, kt_)                                                        \
  do {                                                                             \
    _Pragma("unroll")                                                              \
    for (int it = 0; it < 2; ++it) {                                               \
      const int c = it * 4 + w;                                                    \
      const int r = c * 8 + srow;                                                  \
      load_lds16(Kh + base + (size_t)((kt_) * 64 + r) * 64 + sslot,                \
                 (char*)&Klds[bsel][0] + c * 1024);                                \
      load_lds16(Vt + base + (size_t)r * 1024 + (kt_) * 64 + sslot,                \
                 (char*)&Vlds[bsel][0] + c * 1024);                                \
    }                                                                              \
  } while (0)

  STAGE_KV(0, 0);
  asm volatile("s_waitcnt vmcnt(0)" ::: "memory");
  __syncthreads();
  int cur = 0;

  for (int kt = 0; kt < 16; ++kt) {
    // issue next tile's loads early — they land under this tile's compute
    if (kt + 1 < 16) STAGE_KV(cur ^ 1, kt + 1);

    const bf16_t* Kb = &Klds[cur][0];
    const bf16_t* Vb = &Vlds[cur][0];

    // S' = Q K^T (already includes scale*log2e)
    f32x4 sacc[2][4];
#pragma unroll
    for (int m = 0; m < 2; ++m)
#pragma unroll
      for (int n = 0; n < 4; ++n) sacc[m][n] = f32x4{0.f, 0.f, 0.f, 0.f};
#pragma unroll
    for (int kk = 0; kk < 2; ++kk) {
      bf16x8 kf[4];
#pragma unroll
      for (int n = 0; n < 4; ++n) {
        const int row = n * 16 + lr;
        kf[n] = *(const bf16x8*)((const char*)Kb + row * 128 +
                                 ((kk * 64 + lg * 16) ^ ((row & 7) << 4)));
      }
      __builtin_amdgcn_s_setprio(1);
#pragma unroll
      for (int m = 0; m < 2; ++m)
#pragma unroll
        for (int n = 0; n < 4; ++n)
          sacc[m][n] = mfma16(qf[m][kk], kf[n], sacc[m][n]);
      __builtin_amdgcn_s_setprio(0);
    }

    // online softmax (base-2) with defer-max + P -> swizzled LDS (bf16)
#pragma unroll
    for (int m = 0; m < 2; ++m) {
#pragma unroll
      for (int j = 0; j < 4; ++j) {
        const float s0 = sacc[m][0][j], s1 = sacc[m][1][j];
        const float s2 = sacc[m][2][j], s3 = sacc[m][3][j];
        float tm = fmaxf(fmaxf(fmaxf(s0, s1), s2), s3);
        tm = rmax16(tm);
        const float mold = mreg[m][j];
        // defer-max: skip rescale while tile max stays within 2^11.5 of m
        if (!__all(tm - mold <= RESCALE_THR)) {
          const float mnew = fmaxf(mold, tm);
          const float corr = exp2f(mold - mnew);
          lreg[m][j] *= corr;
#pragma unroll
          for (int n = 0; n < 4; ++n) oacc[m][n][j] *= corr;
          mreg[m][j] = mnew;
        }
        const float mref = mreg[m][j];
        const float p0 = exp2f(s0 - mref), p1 = exp2f(s1 - mref);
        const float p2 = exp2f(s2 - mref), p3 = exp2f(s3 - mref);
        lreg[m][j] += rsum16(p0 + p1 + p2 + p3);
        const int prow = m * 16 + lg * 4 + j;
        const int rx = (prow & 7) << 4;
        char* pb = (char*)Pw + prow * 128;
        *(bf16_t*)(pb + (((0 * 16 + lr) * 2) ^ rx)) = (bf16_t)p0;
        *(bf16_t*)(pb + (((1 * 16 + lr) * 2) ^ rx)) = (bf16_t)p1;
        *(bf16_t*)(pb + (((2 * 16 + lr) * 2) ^ rx)) = (bf16_t)p2;
        *(bf16_t*)(pb + (((3 * 16 + lr) * 2) ^ rx)) = (bf16_t)p3;
      }
    }
    asm volatile("s_waitcnt lgkmcnt(0)" ::: "memory");

    // O += P V  (A = P from Plds, B = V from Vlds[d][kv], both contiguous reads)
#pragma unroll
    for (int kk = 0; kk < 2; ++kk) {
      bf16x8 pf[2], vf[4];
#pragma unroll
      for (int m = 0; m < 2; ++m) {
        const int row = m * 16 + lr;
        pf[m] = *(const bf16x8*)((const char*)Pw + row * 128 +
                                 ((kk * 64 + lg * 16) ^ ((row & 7) << 4)));
      }
#pragma unroll
      for (int n = 0; n < 4; ++n) {
        const int row = n * 16 + lr;
        vf[n] = *(const bf16x8*)((const char*)Vb + row * 128 +
                                 ((kk * 64 + lg * 16) ^ ((row & 7) << 4)));
      }
      __builtin_amdgcn_s_setprio(1);
#pragma unroll
      for (int m = 0; m < 2; ++m)
#pragma unroll
        for (int n = 0; n < 4; ++n)
          oacc[m][n] = mfma16(pf[m], vf[n], oacc[m][n]);
      __builtin_amdgcn_s_setprio(0);
    }

    // single drain per tile: next buffer staged + all waves done reading cur
    asm volatile("s_waitcnt vmcnt(0)" ::: "memory");
    __syncthreads();
    cur ^= 1;
  }
#undef STAGE_KV

  // epilogue: O /= l, write [b][s][h*64+d] bf16
#pragma unroll
  for (int m = 0; m < 2; ++m)
#pragma unroll
    for (int j = 0; j < 4; ++j) {
      const float inv = 1.0f / lreg[m][j];
      const int s = qrow0 + m * 16 + lg * 4 + j;
#pragma unroll
      for (int n = 0; n < 4; ++n)
        Ob[(size_t)(b * 1024 + s) * 1024 + h * 64 + n * 16 + lr] =
            (bf16_t)(oacc[m][n][j] * inv);
    }
}

// ---------------- launch ----------------

extern "C" void kernel_launch(void* const* d_in, const int* in_sizes, int n_in,
                              void* d_out, int out_size, void* d_ws, size_t ws_size,
                              hipStream_t stream) {
  const float* x     = (const float*)d_in[0];
  const float* Wqkv  = (const float*)d_in[1];
  const float* bqkv  = (const float*)d_in[2];
  const float* Wproj = (const float*)d_in[3];
  const float* bproj = (const float*)d_in[4];
  float* out = (float*)d_out;
  char* ws = (char*)d_ws;

  bf16_t* Xb  = (bf16_t*)(ws + OFF_XB);
  bf16_t* Wqt = (bf16_t*)(ws + OFF_WQKVT);
  bf16_t* Wpt = (bf16_t*)(ws + OFF_WPROJT);
  bf16_t* Qh  = (bf16_t*)(ws + OFF_Q);
  bf16_t* Kh  = (bf16_t*)(ws + OFF_K);
  bf16_t* Vt  = (bf16_t*)(ws + OFF_V);
  bf16_t* Ob  = (bf16_t*)(ws + OFF_O);  // aliases Xb (dead after gemm_qkv)

  cvt_bf16_kernel<<<4096, 256, 0, stream>>>(x, Xb, 1048576);
  transpose_cvt<<<dim3(96, 32), dim3(32, 8), 0, stream>>>(Wqkv, Wqt, 1024, 3072);
  transpose_cvt<<<dim3(32, 32), dim3(32, 8), 0, stream>>>(Wproj, Wpt, 1024, 1024);
  gemm_qkv<<<dim3(64, 24), 256, 0, stream>>>(Xb, Wqt, bqkv, Qh, Kh, Vt);
  attn_kernel<<<1024, 256, 0, stream>>>(Qh, Kh, Vt, Ob);
  gemm_out<<<dim3(64, 8), 256, 0, stream>>>(Ob, Wpt, bproj, out);
}

// Round 4
// 195.461 us; speedup vs baseline: 1.6282x; 1.3679x over previous
//
#include <hip/hip_runtime.h>
#include <hip/hip_bf16.h>

typedef __bf16 bf16_t;
typedef __attribute__((ext_vector_type(8))) __bf16 bf16x8;
typedef __attribute__((ext_vector_type(4))) float f32x4;
typedef __attribute__((ext_vector_type(16))) float f32x16;

// dims: B=8 S=1024 D=1024 H=16 hd=64
#define QSCALE 0.18033688011112042f   // (1/sqrt(64)) * log2(e)
#define RESCALE_THR 11.5f             // defer-max threshold in log2 units (~8 nats)

// ws layout (bytes). Ob aliases Xb (Xb dead after gemm_qkv).
#define OFF_XB      ((size_t)0)                       // bf16 [8192][1024]  16.78MB
#define OFF_WQKVT   ((size_t)16777216)                // bf16 [3072][1024]   6.29MB
#define OFF_WPROJT  ((size_t)(16777216 + 6291456))    // bf16 [1024][1024]   2.10MB
#define OFF_Q       ((size_t)(16777216 + 6291456 + 2097152)) // bf16 [128][1024][64]
#define OFF_K       (OFF_Q + (size_t)16777216)
#define OFF_V       (OFF_K + (size_t)16777216)        // transposed: [128][64][1024]
#define OFF_O       OFF_XB                            // bf16 [8192][1024] (alias)

typedef const __attribute__((address_space(1))) void* as1cv;
typedef __attribute__((address_space(3))) void* as3v;

__device__ __forceinline__ void load_lds16(const void* g, void* l) {
  __builtin_amdgcn_global_load_lds((as1cv)g, (as3v)l, 16, 0, 0);
}

__device__ __forceinline__ f32x4 mfma16(bf16x8 a, bf16x8 b, f32x4 c) {
  return __builtin_amdgcn_mfma_f32_16x16x32_bf16(a, b, c, 0, 0, 0);
}
__device__ __forceinline__ f32x16 mfma32(bf16x8 a, bf16x8 b, f32x16 c) {
  return __builtin_amdgcn_mfma_f32_32x32x16_bf16(a, b, c, 0, 0, 0);
}

__device__ __forceinline__ float fexp2(float x) { return __builtin_amdgcn_exp2f(x); }

// pack two f32 -> one u32 of two bf16 (compiler fuses to v_cvt_pk_bf16_f32; m240)
__device__ __forceinline__ unsigned pack2bf(float a, float b) {
  union { bf16_t h[2]; unsigned u; } x;
  x.h[0] = (bf16_t)a; x.h[1] = (bf16_t)b;
  return x.u;
}

__device__ __forceinline__ bf16x8 frag_from_words(unsigned w0, unsigned w1,
                                                  unsigned w2, unsigned w3) {
  union { unsigned u[4]; bf16x8 v; } x;
  x.u[0] = w0; x.u[1] = w1; x.u[2] = w2; x.u[3] = w3;
  return x.v;
}

// swizzled LDS read: 16B at (row, slotbyte) with XOR-(row&7) slot swizzle
__device__ __forceinline__ bf16x8 ldsr(const bf16_t* lds, int row, int slotbyte) {
  return *(const bf16x8*)((const char*)lds + row * 128 +
                          (slotbyte ^ ((row & 7) << 4)));
}

// ---------------- conversion kernels ----------------

__global__ __launch_bounds__(256) void cvt_bf16_kernel(
    const float* __restrict__ in, bf16_t* __restrict__ out, int n8) {
  int i = blockIdx.x * blockDim.x + threadIdx.x;
  if (i >= n8) return;
  const float4* p = (const float4*)in + (size_t)i * 2;
  float4 a = p[0], b = p[1];
  bf16x8 o;
  o[0] = (bf16_t)a.x; o[1] = (bf16_t)a.y; o[2] = (bf16_t)a.z; o[3] = (bf16_t)a.w;
  o[4] = (bf16_t)b.x; o[5] = (bf16_t)b.y; o[6] = (bf16_t)b.z; o[7] = (bf16_t)b.w;
  ((bf16x8*)out)[i] = o;
}

// Wt[n][k] = W[k][n], fp32 -> bf16
__global__ __launch_bounds__(256) void transpose_cvt(
    const float* __restrict__ W, bf16_t* __restrict__ Wt, int rows, int cols) {
  __shared__ float t[32][33];
  const int c0 = blockIdx.x * 32, r0 = blockIdx.y * 32;
  const int tx = threadIdx.x, ty = threadIdx.y;
  for (int rr = ty; rr < 32; rr += 8)
    t[rr][tx] = W[(size_t)(r0 + rr) * cols + c0 + tx];
  __syncthreads();
  for (int rr = ty; rr < 32; rr += 8)
    Wt[(size_t)(c0 + rr) * rows + r0 + tx] = (bf16_t)t[tx][rr];
}

// ---------------- GEMM mainloop (128x128 tile, BK=64, K=1024, lda=ldb=1024) ----------------

__device__ __forceinline__ void gemm_mainloop_1024(
    const bf16_t* __restrict__ A, const bf16_t* __restrict__ Bt,
    int m0, int n0, bf16_t* Alds, bf16_t* Blds, f32x4 acc[4][4]) {
  const int tid = threadIdx.x;
  const int w = tid >> 6, lane = tid & 63;
  const int wr = w >> 1, wc = w & 1;
  const int lr = lane & 15, lg = lane >> 4;
#pragma unroll
  for (int m = 0; m < 4; ++m)
#pragma unroll
    for (int n = 0; n < 4; ++n)
      acc[m][n] = f32x4{0.f, 0.f, 0.f, 0.f};

  const int crow = lane >> 3;        // 0..7 row within 8-row chunk
  const int cels = (lane & 7) * 8;   // element offset within row

  for (int kt = 0; kt < 16; ++kt) {
    const int k0 = kt * 64;
#pragma unroll
    for (int it = 0; it < 4; ++it) {
      const int c = it * 4 + w;                // chunk 0..15, uniform per wave
      const int rA = c * 8 + crow;             // tile row 0..127
      load_lds16(A + (size_t)(m0 + rA) * 1024 + k0 + cels, (char*)Alds + c * 1024);
      load_lds16(Bt + (size_t)(n0 + rA) * 1024 + k0 + cels, (char*)Blds + c * 1024);
    }
    asm volatile("s_waitcnt vmcnt(0)" ::: "memory");
    __syncthreads();

    bf16x8 af[4][2], bfr[4][2];
#pragma unroll
    for (int m = 0; m < 4; ++m)
#pragma unroll
      for (int kk = 0; kk < 2; ++kk)
        af[m][kk] = *(const bf16x8*)(Alds + (wr * 64 + m * 16 + lr) * 64 + kk * 32 + lg * 8);
#pragma unroll
    for (int n = 0; n < 4; ++n)
#pragma unroll
      for (int kk = 0; kk < 2; ++kk)
        bfr[n][kk] = *(const bf16x8*)(Blds + (wc * 64 + n * 16 + lr) * 64 + kk * 32 + lg * 8);
#pragma unroll
    for (int kk = 0; kk < 2; ++kk)
#pragma unroll
      for (int m = 0; m < 4; ++m)
#pragma unroll
        for (int n = 0; n < 4; ++n)
          acc[m][n] = mfma16(af[m][kk], bfr[n][kk], acc[m][n]);
    __syncthreads();
  }
}

// ---------------- GEMM1: X @ Wqkv^T -> scatter Q(scaled)/K/V(transposed) bf16 ----------------

__global__ __launch_bounds__(256) void gemm_qkv(
    const bf16_t* __restrict__ A, const bf16_t* __restrict__ Bt,
    const float* __restrict__ bias,
    bf16_t* __restrict__ Qh, bf16_t* __restrict__ Kh, bf16_t* __restrict__ Vt) {
  __shared__ alignas(128) bf16_t Alds[128 * 64];
  __shared__ alignas(128) bf16_t Blds[128 * 64];
  const int m0 = blockIdx.x * 128, n0 = blockIdx.y * 128;
  f32x4 acc[4][4];
  gemm_mainloop_1024(A, Bt, m0, n0, Alds, Blds, acc);

  const int tid = threadIdx.x, w = tid >> 6, lane = tid & 63;
  const int wr = w >> 1, wc = w & 1, lr = lane & 15, lg = lane >> 4;
  const int section = n0 >> 10;  // 0=Q 1=K 2=V (uniform per block)
#pragma unroll
  for (int n = 0; n < 4; ++n) {
    const int c = n0 + wc * 64 + n * 16 + lr;   // global col in [0,3072)
    const float bi = bias[c];
    const int d1024 = c & 1023;
    const int h = d1024 >> 6, d = d1024 & 63;
#pragma unroll
    for (int m = 0; m < 4; ++m) {
#pragma unroll
      for (int j = 0; j < 4; ++j) {
        const int r = m0 + wr * 64 + m * 16 + lg * 4 + j;  // token index
        const int b = r >> 10, s = r & 1023;
        const size_t hb = ((size_t)(b * 16 + h)) << 16;
        const float v = acc[m][n][j] + bi;
        if (section == 0)      Qh[hb + (size_t)s * 64 + d] = (bf16_t)(v * QSCALE);
        else if (section == 1) Kh[hb + (size_t)s * 64 + d] = (bf16_t)v;
        else                   Vt[hb + (size_t)d * 1024 + s] = (bf16_t)v;
      }
    }
  }
}

// ---------------- GEMM2: O @ Wproj^T + b -> fp32 out ----------------

__global__ __launch_bounds__(256) void gemm_out(
    const bf16_t* __restrict__ A, const bf16_t* __restrict__ Bt,
    const float* __restrict__ bias, float* __restrict__ out) {
  __shared__ alignas(128) bf16_t Alds[128 * 64];
  __shared__ alignas(128) bf16_t Blds[128 * 64];
  const int m0 = blockIdx.x * 128, n0 = blockIdx.y * 128;
  f32x4 acc[4][4];
  gemm_mainloop_1024(A, Bt, m0, n0, Alds, Blds, acc);

  const int tid = threadIdx.x, w = tid >> 6, lane = tid & 63;
  const int wr = w >> 1, wc = w & 1, lr = lane & 15, lg = lane >> 4;
#pragma unroll
  for (int n = 0; n < 4; ++n) {
    const int c = n0 + wc * 64 + n * 16 + lr;
    const float bi = bias[c];
#pragma unroll
    for (int m = 0; m < 4; ++m)
#pragma unroll
      for (int j = 0; j < 4; ++j) {
        const int r = m0 + wr * 64 + m * 16 + lg * 4 + j;
        out[(size_t)r * 1024 + c] = acc[m][n][j] + bi;
      }
  }
}

// ---------------- flash attention, swapped-operand (m214/T12 structure) ----------------
// 4 waves x 32 q-rows. KVBLK=64, dbuf LDS. QK^T computed as St = K·Q^T so each
// lane owns one q-row (col = lane&31); softmax is in-register (tree + 1 shfl_xor(32)).
// P -> PV B-frags via pack2bf + v_permlane32_swap (no P LDS round-trip).
// PV computed as O^T = V^T·P^T so rescale corr is a per-lane scalar.
// permlane operand order: dst = LOW kv pair, src = HIGH kv pair (m214 recipe;
// dst' = [dst_lo, src_lo], src' = [dst_hi, src_hi]).

__global__ __launch_bounds__(256, 4) void attn_kernel(
    const bf16_t* __restrict__ Qh, const bf16_t* __restrict__ Kh,
    const bf16_t* __restrict__ Vt, bf16_t* __restrict__ Ob) {
  __shared__ alignas(128) bf16_t Klds[2][64 * 64];  // [kv][d], XOR-swizzled slots
  __shared__ alignas(128) bf16_t Vlds[2][64 * 64];  // [d][kv], XOR-swizzled slots

  // XCD-aware remap: all 8 q-tiles of one head land on one XCD (T1)
  const int x = blockIdx.x;                // 0..1023
  const int bh = ((x & 7) << 4) | (x >> 6);
  const int qt = (x >> 3) & 7;
  const int b = bh >> 4, h = bh & 15;
  const int tid = threadIdx.x, w = tid >> 6, lane = tid & 63;
  const int q31 = lane & 31, hi = lane >> 5;
  const size_t base = (size_t)bh << 16;    // 65536 elements per head

  const int qrow0 = qt * 128 + w * 32;

  // Q fragments (B-operand of swapped QK^T): qf[c][j] = Q[qrow0+q31][hi*8 + j + 16c]
  bf16x8 qf[4];
#pragma unroll
  for (int c = 0; c < 4; ++c)
    qf[c] = *(const bf16x8*)(Qh + base + (size_t)(qrow0 + q31) * 64 + hi * 8 + 16 * c);

  f32x16 oacc0, oacc1;
#pragma unroll
  for (int r = 0; r < 16; ++r) { oacc0[r] = 0.f; oacc1[r] = 0.f; }
  float mreg = -1e30f, lreg = 0.f;

  // staging geometry (identical to verified R1/R2 both-sides swizzle)
  const int srow = lane >> 3;                    // 0..7
  const int sslot = (((lane & 7) ^ srow) << 3);  // swizzled element offset

#define STAGE_KV(bsel, kt_)                                                        \
  do {                                                                             \
    _Pragma("unroll")                                                              \
    for (int it = 0; it < 2; ++it) {                                               \
      const int c = it * 4 + w;                                                    \
      const int r = c * 8 + srow;                                                  \
      load_lds16(Kh + base + (size_t)((kt_) * 64 + r) * 64 + sslot,                \
                 (char*)&Klds[bsel][0] + c * 1024);                                \
      load_lds16(Vt + base + (size_t)r * 1024 + (kt_) * 64 + sslot,                \
                 (char*)&Vlds[bsel][0] + c * 1024);                                \
    }                                                                              \
  } while (0)

  STAGE_KV(0, 0);
  asm volatile("s_waitcnt vmcnt(0)" ::: "memory");
  __syncthreads();
  int cur = 0;

  for (int kt = 0; kt < 16; ++kt) {
    if (kt + 1 < 16) STAGE_KV(cur ^ 1, kt + 1);

    const bf16_t* Kb = &Klds[cur][0];
    const bf16_t* Vb = &Vlds[cur][0];

    // St = K · Q^T : st0 = kv rows [0,32), st1 = [32,64); lane holds col q=q31,
    // rows (reg&3)+8*(reg>>2)+4*hi (verified D-layout m74/m101)
    f32x16 st0, st1;
#pragma unroll
    for (int r = 0; r < 16; ++r) { st0[r] = 0.f; st1[r] = 0.f; }
#pragma unroll
    for (int c = 0; c < 4; ++c) {
      const int sb = hi * 16 + 32 * c;
      bf16x8 k0 = ldsr(Kb, q31, sb);
      bf16x8 k1 = ldsr(Kb, 32 + q31, sb);
      __builtin_amdgcn_s_setprio(1);
      st0 = mfma32(k0, qf[c], st0);
      st1 = mfma32(k1, qf[c], st1);
      __builtin_amdgcn_s_setprio(0);
    }

    // ---- in-register online softmax (one q-row per lane) ----
    float mx[8];
#pragma unroll
    for (int r = 0; r < 8; ++r)
      mx[r] = fmaxf(fmaxf(st0[r], st0[r + 8]), fmaxf(st1[r], st1[r + 8]));
#pragma unroll
    for (int r = 0; r < 4; ++r) mx[r] = fmaxf(mx[r], mx[r + 4]);
    float tm = fmaxf(fmaxf(mx[0], mx[1]), fmaxf(mx[2], mx[3]));
    tm = fmaxf(tm, __shfl_xor(tm, 32));

    if (!__all(tm - mreg <= RESCALE_THR)) {
      const float mnew = fmaxf(mreg, tm);
      const float corr = fexp2(mreg - mnew);
      lreg *= corr;
#pragma unroll
      for (int r = 0; r < 16; ++r) { oacc0[r] *= corr; oacc1[r] *= corr; }
      mreg = mnew;
    }

    // exp + sum + build PV B-frags via permlane32_swap (T12).
    // dst = pack(LOW kv pair), src = pack(HIGH kv pair):
    //   dst' = [dst_lo, src_lo] -> word for kv-chunk base
    //   src' = [dst_hi, src_hi] -> word for kv-chunk base+8
    bf16x8 pa[4];
    float psum = 0.f;
#define GROUP(KC, STV, BASE)                                                   \
    {                                                                          \
      const float e0 = fexp2(STV[BASE + 0] - mreg);                            \
      const float e1 = fexp2(STV[BASE + 1] - mreg);                            \
      const float e2 = fexp2(STV[BASE + 2] - mreg);                            \
      const float e3 = fexp2(STV[BASE + 3] - mreg);                            \
      const float e4 = fexp2(STV[BASE + 4] - mreg);                            \
      const float e5 = fexp2(STV[BASE + 5] - mreg);                            \
      const float e6 = fexp2(STV[BASE + 6] - mreg);                            \
      const float e7 = fexp2(STV[BASE + 7] - mreg);                            \
      psum += ((e0 + e1) + (e2 + e3)) + ((e4 + e5) + (e6 + e7));               \
      unsigned wa = pack2bf(e0, e1), wb = pack2bf(e4, e5);                     \
      asm volatile("v_permlane32_swap_b32 %0, %1" : "+v"(wa), "+v"(wb));       \
      unsigned wc = pack2bf(e2, e3), wd = pack2bf(e6, e7);                     \
      asm volatile("v_permlane32_swap_b32 %0, %1" : "+v"(wc), "+v"(wd));       \
      pa[KC] = frag_from_words(wa, wc, wb, wd);                                \
    }
    GROUP(0, st0, 0)
    GROUP(1, st0, 8)
    GROUP(2, st1, 0)
    GROUP(3, st1, 8)
#undef GROUP
    lreg += psum + __shfl_xor(psum, 32);

    // O^T += V^T · P^T  (A = V^T rows d from Vlds, B = pa; out col = q = q31)
#pragma unroll
    for (int kc = 0; kc < 4; ++kc) {
      const int sb = hi * 16 + 32 * kc;
      bf16x8 v0 = ldsr(Vb, q31, sb);
      bf16x8 v1 = ldsr(Vb, 32 + q31, sb);
      __builtin_amdgcn_s_setprio(1);
      oacc0 = mfma32(v0, pa[kc], oacc0);
      oacc1 = mfma32(v1, pa[kc], oacc1);
      __builtin_amdgcn_s_setprio(0);
    }

    asm volatile("s_waitcnt vmcnt(0)" ::: "memory");
    __syncthreads();
    cur ^= 1;
  }
#undef STAGE_KV

  // epilogue: O = O^T / l ; lane writes row s=qrow0+q31, d = 32n + row(reg,hi)
  const float inv = 1.0f / lreg;
  const int s_tok = qrow0 + q31;
  bf16_t* obase = Ob + (size_t)(b * 1024 + s_tok) * 1024 + h * 64;
#pragma unroll
  for (int i = 0; i < 8; ++i) {
    const int dbase = ((2 * i) & 3) + 8 * ((2 * i) >> 2) + 4 * hi;
    *(unsigned*)(obase + dbase) =
        pack2bf(oacc0[2 * i] * inv, oacc0[2 * i + 1] * inv);
    *(unsigned*)(obase + 32 + dbase) =
        pack2bf(oacc1[2 * i] * inv, oacc1[2 * i + 1] * inv);
  }
}

// ---------------- launch ----------------

extern "C" void kernel_launch(void* const* d_in, const int* in_sizes, int n_in,
                              void* d_out, int out_size, void* d_ws, size_t ws_size,
                              hipStream_t stream) {
  const float* x     = (const float*)d_in[0];
  const float* Wqkv  = (const float*)d_in[1];
  const float* bqkv  = (const float*)d_in[2];
  const float* Wproj = (const float*)d_in[3];
  const float* bproj = (const float*)d_in[4];
  float* out = (float*)d_out;
  char* ws = (char*)d_ws;

  bf16_t* Xb  = (bf16_t*)(ws + OFF_XB);
  bf16_t* Wqt = (bf16_t*)(ws + OFF_WQKVT);
  bf16_t* Wpt = (bf16_t*)(ws + OFF_WPROJT);
  bf16_t* Qh  = (bf16_t*)(ws + OFF_Q);
  bf16_t* Kh  = (bf16_t*)(ws + OFF_K);
  bf16_t* Vt  = (bf16_t*)(ws + OFF_V);
  bf16_t* Ob  = (bf16_t*)(ws + OFF_O);  // aliases Xb (dead after gemm_qkv)

  cvt_bf16_kernel<<<4096, 256, 0, stream>>>(x, Xb, 1048576);
  transpose_cvt<<<dim3(96, 32), dim3(32, 8), 0, stream>>>(Wqkv, Wqt, 1024, 3072);
  transpose_cvt<<<dim3(32, 32), dim3(32, 8), 0, stream>>>(Wproj, Wpt, 1024, 1024);
  gemm_qkv<<<dim3(64, 24), 256, 0, stream>>>(Xb, Wqt, bqkv, Qh, Kh, Vt);
  attn_kernel<<<1024, 256, 0, stream>>>(Qh, Kh, Vt, Ob);
  gemm_out<<<dim3(64, 8), 256, 0, stream>>>(Ob, Wpt, bproj, out);
}

// Round 5
// 179.030 us; speedup vs baseline: 1.7776x; 1.0918x over previous
//
#include <hip/hip_runtime.h>
#include <hip/hip_bf16.h>

typedef __bf16 bf16_t;
typedef __attribute__((ext_vector_type(8))) __bf16 bf16x8;
typedef __attribute__((ext_vector_type(4))) float f32x4;
typedef __attribute__((ext_vector_type(16))) float f32x16;

// dims: B=8 S=1024 D=1024 H=16 hd=64
#define QSCALE 0.18033688011112042f   // (1/sqrt(64)) * log2(e)
#define RESCALE_THR 11.5f             // defer-max threshold in log2 units (~8 nats)

// ws layout (bytes). Ob aliases Xb (Xb dead after gemm_qkv).
#define OFF_XB      ((size_t)0)                       // bf16 [8192][1024]  16.78MB
#define OFF_WQKVT   ((size_t)16777216)                // bf16 [3072][1024]   6.29MB
#define OFF_WPROJT  ((size_t)(16777216 + 6291456))    // bf16 [1024][1024]   2.10MB
#define OFF_Q       ((size_t)(16777216 + 6291456 + 2097152)) // bf16 [128][1024][64]
#define OFF_K       (OFF_Q + (size_t)16777216)
#define OFF_V       (OFF_K + (size_t)16777216)        // transposed: [128][64][1024]
#define OFF_O       OFF_XB                            // bf16 [8192][1024] (alias)

typedef const __attribute__((address_space(1))) void* as1cv;
typedef __attribute__((address_space(3))) void* as3v;

__device__ __forceinline__ void load_lds16(const void* g, void* l) {
  __builtin_amdgcn_global_load_lds((as1cv)g, (as3v)l, 16, 0, 0);
}

__device__ __forceinline__ f32x4 mfma16(bf16x8 a, bf16x8 b, f32x4 c) {
  return __builtin_amdgcn_mfma_f32_16x16x32_bf16(a, b, c, 0, 0, 0);
}
__device__ __forceinline__ f32x16 mfma32(bf16x8 a, bf16x8 b, f32x16 c) {
  return __builtin_amdgcn_mfma_f32_32x32x16_bf16(a, b, c, 0, 0, 0);
}

__device__ __forceinline__ float fexp2(float x) { return __builtin_amdgcn_exp2f(x); }

// pack two f32 -> one u32 of two bf16 (compiler fuses to v_cvt_pk_bf16_f32; m240)
__device__ __forceinline__ unsigned pack2bf(float a, float b) {
  union { bf16_t h[2]; unsigned u; } x;
  x.h[0] = (bf16_t)a; x.h[1] = (bf16_t)b;
  return x.u;
}

__device__ __forceinline__ bf16x8 frag_from_words(unsigned w0, unsigned w1,
                                                  unsigned w2, unsigned w3) {
  union { unsigned u[4]; bf16x8 v; } x;
  x.u[0] = w0; x.u[1] = w1; x.u[2] = w2; x.u[3] = w3;
  return x.v;
}

// swizzled LDS read: 16B at (row, slotbyte) with XOR-(row&7) slot swizzle
__device__ __forceinline__ bf16x8 ldsr(const bf16_t* lds, int row, int slotbyte) {
  return *(const bf16x8*)((const char*)lds + row * 128 +
                          (slotbyte ^ ((row & 7) << 4)));
}

// ---------------- conversion kernels ----------------

__global__ __launch_bounds__(256) void cvt_bf16_kernel(
    const float* __restrict__ in, bf16_t* __restrict__ out, int n8) {
  int i = blockIdx.x * blockDim.x + threadIdx.x;
  if (i >= n8) return;
  const float4* p = (const float4*)in + (size_t)i * 2;
  float4 a = p[0], b = p[1];
  bf16x8 o;
  o[0] = (bf16_t)a.x; o[1] = (bf16_t)a.y; o[2] = (bf16_t)a.z; o[3] = (bf16_t)a.w;
  o[4] = (bf16_t)b.x; o[5] = (bf16_t)b.y; o[6] = (bf16_t)b.z; o[7] = (bf16_t)b.w;
  ((bf16x8*)out)[i] = o;
}

// Wt[n][k] = W[k][n], fp32 -> bf16
__global__ __launch_bounds__(256) void transpose_cvt(
    const float* __restrict__ W, bf16_t* __restrict__ Wt, int rows, int cols) {
  __shared__ float t[32][33];
  const int c0 = blockIdx.x * 32, r0 = blockIdx.y * 32;
  const int tx = threadIdx.x, ty = threadIdx.y;
  for (int rr = ty; rr < 32; rr += 8)
    t[rr][tx] = W[(size_t)(r0 + rr) * cols + c0 + tx];
  __syncthreads();
  for (int rr = ty; rr < 32; rr += 8)
    Wt[(size_t)(c0 + rr) * rows + r0 + tx] = (bf16_t)t[tx][rr];
}

// ---------------- GEMM mainloop (128x128 tile, BK=64, K=1024, lda=ldb=1024) ----------------
// LDS tiles XOR-swizzled both-sides (rule #21): pre-swizzled global source slot
// + linear global_load_lds dest, fragment reads XOR (row&7)<<4. Kills the
// 16-way ds_read_b128 conflict (R4: SQ_LDS_BANK_CONFLICT=1.9e7 on this loop).

__device__ __forceinline__ void gemm_mainloop_1024(
    const bf16_t* __restrict__ A, const bf16_t* __restrict__ Bt,
    int m0, int n0, bf16_t* Alds, bf16_t* Blds, f32x4 acc[4][4]) {
  const int tid = threadIdx.x;
  const int w = tid >> 6, lane = tid & 63;
  const int wr = w >> 1, wc = w & 1;
  const int lr = lane & 15, lg = lane >> 4;
#pragma unroll
  for (int m = 0; m < 4; ++m)
#pragma unroll
    for (int n = 0; n < 4; ++n)
      acc[m][n] = f32x4{0.f, 0.f, 0.f, 0.f};

  const int crow = lane >> 3;                    // 0..7 row within 8-row chunk
  const int cels = (((lane & 7) ^ crow) * 8);    // pre-swizzled source slot
  const int rx = (lr & 7) << 4;                  // fragment-read XOR key

  for (int kt = 0; kt < 16; ++kt) {
    const int k0 = kt * 64;
#pragma unroll
    for (int it = 0; it < 4; ++it) {
      const int c = it * 4 + w;                // chunk 0..15, uniform per wave
      const int rA = c * 8 + crow;             // tile row 0..127
      load_lds16(A + (size_t)(m0 + rA) * 1024 + k0 + cels, (char*)Alds + c * 1024);
      load_lds16(Bt + (size_t)(n0 + rA) * 1024 + k0 + cels, (char*)Blds + c * 1024);
    }
    asm volatile("s_waitcnt vmcnt(0)" ::: "memory");
    __syncthreads();

    bf16x8 af[4][2], bfr[4][2];
#pragma unroll
    for (int m = 0; m < 4; ++m)
#pragma unroll
      for (int kk = 0; kk < 2; ++kk)
        af[m][kk] = *(const bf16x8*)((const char*)Alds + (wr * 64 + m * 16 + lr) * 128 +
                                     ((kk * 64 + lg * 16) ^ rx));
#pragma unroll
    for (int n = 0; n < 4; ++n)
#pragma unroll
      for (int kk = 0; kk < 2; ++kk)
        bfr[n][kk] = *(const bf16x8*)((const char*)Blds + (wc * 64 + n * 16 + lr) * 128 +
                                      ((kk * 64 + lg * 16) ^ rx));
#pragma unroll
    for (int kk = 0; kk < 2; ++kk)
#pragma unroll
      for (int m = 0; m < 4; ++m)
#pragma unroll
        for (int n = 0; n < 4; ++n)
          acc[m][n] = mfma16(af[m][kk], bfr[n][kk], acc[m][n]);
    __syncthreads();
  }
}

// ---------------- GEMM1: X @ Wqkv^T -> scatter Q(scaled)/K/V(transposed) bf16 ----------------

__global__ __launch_bounds__(256) void gemm_qkv(
    const bf16_t* __restrict__ A, const bf16_t* __restrict__ Bt,
    const float* __restrict__ bias,
    bf16_t* __restrict__ Qh, bf16_t* __restrict__ Kh, bf16_t* __restrict__ Vt) {
  __shared__ alignas(128) bf16_t Alds[128 * 64];
  __shared__ alignas(128) bf16_t Blds[128 * 64];
  const int m0 = blockIdx.x * 128, n0 = blockIdx.y * 128;
  f32x4 acc[4][4];
  gemm_mainloop_1024(A, Bt, m0, n0, Alds, Blds, acc);

  const int tid = threadIdx.x, w = tid >> 6, lane = tid & 63;
  const int wr = w >> 1, wc = w & 1, lr = lane & 15, lg = lane >> 4;
  const int section = n0 >> 10;  // 0=Q 1=K 2=V (uniform per block)
#pragma unroll
  for (int n = 0; n < 4; ++n) {
    const int c = n0 + wc * 64 + n * 16 + lr;   // global col in [0,3072)
    const float bi = bias[c];
    const int d1024 = c & 1023;
    const int h = d1024 >> 6, d = d1024 & 63;
#pragma unroll
    for (int m = 0; m < 4; ++m) {
#pragma unroll
      for (int j = 0; j < 4; ++j) {
        const int r = m0 + wr * 64 + m * 16 + lg * 4 + j;  // token index
        const int b = r >> 10, s = r & 1023;
        const size_t hb = ((size_t)(b * 16 + h)) << 16;
        const float v = acc[m][n][j] + bi;
        if (section == 0)      Qh[hb + (size_t)s * 64 + d] = (bf16_t)(v * QSCALE);
        else if (section == 1) Kh[hb + (size_t)s * 64 + d] = (bf16_t)v;
        else                   Vt[hb + (size_t)d * 1024 + s] = (bf16_t)v;
      }
    }
  }
}

// ---------------- GEMM2: O @ Wproj^T + b -> fp32 out ----------------

__global__ __launch_bounds__(256) void gemm_out(
    const bf16_t* __restrict__ A, const bf16_t* __restrict__ Bt,
    const float* __restrict__ bias, float* __restrict__ out) {
  __shared__ alignas(128) bf16_t Alds[128 * 64];
  __shared__ alignas(128) bf16_t Blds[128 * 64];
  const int m0 = blockIdx.x * 128, n0 = blockIdx.y * 128;
  f32x4 acc[4][4];
  gemm_mainloop_1024(A, Bt, m0, n0, Alds, Blds, acc);

  const int tid = threadIdx.x, w = tid >> 6, lane = tid & 63;
  const int wr = w >> 1, wc = w & 1, lr = lane & 15, lg = lane >> 4;
#pragma unroll
  for (int n = 0; n < 4; ++n) {
    const int c = n0 + wc * 64 + n * 16 + lr;
    const float bi = bias[c];
#pragma unroll
    for (int m = 0; m < 4; ++m)
#pragma unroll
      for (int j = 0; j < 4; ++j) {
        const int r = m0 + wr * 64 + m * 16 + lg * 4 + j;
        out[(size_t)r * 1024 + c] = acc[m][n][j] + bi;
      }
  }
}

// ---------------- flash attention, swapped-operand (m214/T12 structure) ----------------
// 4 waves x 32 q-rows. KVBLK=64, dbuf LDS. QK^T computed as St = K·Q^T so each
// lane owns one q-row (col = lane&31); softmax is in-register (tree + 1 shfl_xor(32)).
// P -> PV B-frags via pack2bf + v_permlane32_swap (no P LDS round-trip).
// PV computed as O^T = V^T·P^T so rescale corr is a per-lane scalar.
// permlane operand order: dst = LOW kv pair, src = HIGH kv pair (m214 recipe;
// dst' = [dst_lo, src_lo], src' = [dst_hi, src_hi]).

__global__ __launch_bounds__(256, 4) void attn_kernel(
    const bf16_t* __restrict__ Qh, const bf16_t* __restrict__ Kh,
    const bf16_t* __restrict__ Vt, bf16_t* __restrict__ Ob) {
  __shared__ alignas(128) bf16_t Klds[2][64 * 64];  // [kv][d], XOR-swizzled slots
  __shared__ alignas(128) bf16_t Vlds[2][64 * 64];  // [d][kv], XOR-swizzled slots

  // XCD-aware remap: all 8 q-tiles of one head land on one XCD (T1)
  const int x = blockIdx.x;                // 0..1023
  const int bh = ((x & 7) << 4) | (x >> 6);
  const int qt = (x >> 3) & 7;
  const int b = bh >> 4, h = bh & 15;
  const int tid = threadIdx.x, w = tid >> 6, lane = tid & 63;
  const int q31 = lane & 31, hi = lane >> 5;
  const size_t base = (size_t)bh << 16;    // 65536 elements per head

  const int qrow0 = qt * 128 + w * 32;

  // Q fragments (B-operand of swapped QK^T): qf[c][j] = Q[qrow0+q31][hi*8 + j + 16c]
  bf16x8 qf[4];
#pragma unroll
  for (int c = 0; c < 4; ++c)
    qf[c] = *(const bf16x8*)(Qh + base + (size_t)(qrow0 + q31) * 64 + hi * 8 + 16 * c);

  f32x16 oacc0, oacc1;
#pragma unroll
  for (int r = 0; r < 16; ++r) { oacc0[r] = 0.f; oacc1[r] = 0.f; }
  float mreg = -1e30f, lreg = 0.f;

  // staging geometry (both-sides swizzle, rule #21)
  const int srow = lane >> 3;                    // 0..7
  const int sslot = (((lane & 7) ^ srow) << 3);  // swizzled element offset

#define STAGE_KV(bsel, kt_)                                                        \
  do {                                                                             \
    _Pragma("unroll")                                                              \
    for (int it = 0; it < 2; ++it) {                                               \
      const int c = it * 4 + w;                                                    \
      const int r = c * 8 + srow;                                                  \
      load_lds16(Kh + base + (size_t)((kt_) * 64 + r) * 64 + sslot,                \
                 (char*)&Klds[bsel][0] + c * 1024);                                \
      load_lds16(Vt + base + (size_t)r * 1024 + (kt_) * 64 + sslot,                \
                 (char*)&Vlds[bsel][0] + c * 1024);                                \
    }                                                                              \
  } while (0)

  STAGE_KV(0, 0);
  asm volatile("s_waitcnt vmcnt(0)" ::: "memory");
  __syncthreads();
  int cur = 0;

  for (int kt = 0; kt < 16; ++kt) {
    if (kt + 1 < 16) STAGE_KV(cur ^ 1, kt + 1);

    const bf16_t* Kb = &Klds[cur][0];
    const bf16_t* Vb = &Vlds[cur][0];

    // St = K · Q^T : st0 = kv rows [0,32), st1 = [32,64); lane holds col q=q31,
    // rows (reg&3)+8*(reg>>2)+4*hi (verified D-layout m74/m101)
    f32x16 st0, st1;
#pragma unroll
    for (int r = 0; r < 16; ++r) { st0[r] = 0.f; st1[r] = 0.f; }
#pragma unroll
    for (int c = 0; c < 4; ++c) {
      const int sb = hi * 16 + 32 * c;
      bf16x8 k0 = ldsr(Kb, q31, sb);
      bf16x8 k1 = ldsr(Kb, 32 + q31, sb);
      __builtin_amdgcn_s_setprio(1);
      st0 = mfma32(k0, qf[c], st0);
      st1 = mfma32(k1, qf[c], st1);
      __builtin_amdgcn_s_setprio(0);
    }

    // ---- in-register online softmax (one q-row per lane) ----
    float mx[8];
#pragma unroll
    for (int r = 0; r < 8; ++r)
      mx[r] = fmaxf(fmaxf(st0[r], st0[r + 8]), fmaxf(st1[r], st1[r + 8]));
#pragma unroll
    for (int r = 0; r < 4; ++r) mx[r] = fmaxf(mx[r], mx[r + 4]);
    float tm = fmaxf(fmaxf(mx[0], mx[1]), fmaxf(mx[2], mx[3]));
    tm = fmaxf(tm, __shfl_xor(tm, 32));

    if (!__all(tm - mreg <= RESCALE_THR)) {
      const float mnew = fmaxf(mreg, tm);
      const float corr = fexp2(mreg - mnew);
      lreg *= corr;
#pragma unroll
      for (int r = 0; r < 16; ++r) { oacc0[r] *= corr; oacc1[r] *= corr; }
      mreg = mnew;
    }

    // exp + sum + build PV B-frags via permlane32_swap (T12).
    // dst = pack(LOW kv pair), src = pack(HIGH kv pair):
    //   dst' = [dst_lo, src_lo] -> word for kv-chunk base
    //   src' = [dst_hi, src_hi] -> word for kv-chunk base+8
    bf16x8 pa[4];
    float psum = 0.f;
#define GROUP(KC, STV, BASE)                                                   \
    {                                                                          \
      const float e0 = fexp2(STV[BASE + 0] - mreg);                            \
      const float e1 = fexp2(STV[BASE + 1] - mreg);                            \
      const float e2 = fexp2(STV[BASE + 2] - mreg);                            \
      const float e3 = fexp2(STV[BASE + 3] - mreg);                            \
      const float e4 = fexp2(STV[BASE + 4] - mreg);                            \
      const float e5 = fexp2(STV[BASE + 5] - mreg);                            \
      const float e6 = fexp2(STV[BASE + 6] - mreg);                            \
      const float e7 = fexp2(STV[BASE + 7] - mreg);                            \
      psum += ((e0 + e1) + (e2 + e3)) + ((e4 + e5) + (e6 + e7));               \
      unsigned wa = pack2bf(e0, e1), wb = pack2bf(e4, e5);                     \
      asm volatile("v_permlane32_swap_b32 %0, %1" : "+v"(wa), "+v"(wb));       \
      unsigned wc = pack2bf(e2, e3), wd = pack2bf(e6, e7);                     \
      asm volatile("v_permlane32_swap_b32 %0, %1" : "+v"(wc), "+v"(wd));       \
      pa[KC] = frag_from_words(wa, wc, wb, wd);                                \
    }
    GROUP(0, st0, 0)
    GROUP(1, st0, 8)
    GROUP(2, st1, 0)
    GROUP(3, st1, 8)
#undef GROUP
    lreg += psum + __shfl_xor(psum, 32);

    // O^T += V^T · P^T  (A = V^T rows d from Vlds, B = pa; out col = q = q31)
#pragma unroll
    for (int kc = 0; kc < 4; ++kc) {
      const int sb = hi * 16 + 32 * kc;
      bf16x8 v0 = ldsr(Vb, q31, sb);
      bf16x8 v1 = ldsr(Vb, 32 + q31, sb);
      __builtin_amdgcn_s_setprio(1);
      oacc0 = mfma32(v0, pa[kc], oacc0);
      oacc1 = mfma32(v1, pa[kc], oacc1);
      __builtin_amdgcn_s_setprio(0);
    }

    asm volatile("s_waitcnt vmcnt(0)" ::: "memory");
    __syncthreads();
    cur ^= 1;
  }
#undef STAGE_KV

  // epilogue: O = O^T / l ; lane writes row s=qrow0+q31, d = 32n + row(reg,hi)
  const float inv = 1.0f / lreg;
  const int s_tok = qrow0 + q31;
  bf16_t* obase = Ob + (size_t)(b * 1024 + s_tok) * 1024 + h * 64;
#pragma unroll
  for (int i = 0; i < 8; ++i) {
    const int dbase = ((2 * i) & 3) + 8 * ((2 * i) >> 2) + 4 * hi;
    *(unsigned*)(obase + dbase) =
        pack2bf(oacc0[2 * i] * inv, oacc0[2 * i + 1] * inv);
    *(unsigned*)(obase + 32 + dbase) =
        pack2bf(oacc1[2 * i] * inv, oacc1[2 * i + 1] * inv);
  }
}

// ---------------- launch ----------------

extern "C" void kernel_launch(void* const* d_in, const int* in_sizes, int n_in,
                              void* d_out, int out_size, void* d_ws, size_t ws_size,
                              hipStream_t stream) {
  const float* x     = (const float*)d_in[0];
  const float* Wqkv  = (const float*)d_in[1];
  const float* bqkv  = (const float*)d_in[2];
  const float* Wproj = (const float*)d_in[3];
  const float* bproj = (const float*)d_in[4];
  float* out = (float*)d_out;
  char* ws = (char*)d_ws;

  bf16_t* Xb  = (bf16_t*)(ws + OFF_XB);
  bf16_t* Wqt = (bf16_t*)(ws + OFF_WQKVT);
  bf16_t* Wpt = (bf16_t*)(ws + OFF_WPROJT);
  bf16_t* Qh  = (bf16_t*)(ws + OFF_Q);
  bf16_t* Kh  = (bf16_t*)(ws + OFF_K);
  bf16_t* Vt  = (bf16_t*)(ws + OFF_V);
  bf16_t* Ob  = (bf16_t*)(ws + OFF_O);  // aliases Xb (dead after gemm_qkv)

  cvt_bf16_kernel<<<4096, 256, 0, stream>>>(x, Xb, 1048576);
  transpose_cvt<<<dim3(96, 32), dim3(32, 8), 0, stream>>>(Wqkv, Wqt, 1024, 3072);
  transpose_cvt<<<dim3(32, 32), dim3(32, 8), 0, stream>>>(Wproj, Wpt, 1024, 1024);
  gemm_qkv<<<dim3(64, 24), 256, 0, stream>>>(Xb, Wqt, bqkv, Qh, Kh, Vt);
  attn_kernel<<<1024, 256, 0, stream>>>(Qh, Kh, Vt, Ob);
  gemm_out<<<dim3(64, 8), 256, 0, stream>>>(Ob, Wpt, bproj, out);
}